// Round 7
// baseline (138.087 us; speedup 1.0000x reference)
//
#include <hip/hip_runtime.h>

#define Bn 16
#define Cn 64
#define Hn 128
#define Wn 128
#define HWn (Hn * Wn)

typedef __attribute__((ext_vector_type(8)))  short  short8;    // 8 bf16
typedef __attribute__((ext_vector_type(16))) float  floatx16;  // 32x32 C/D
typedef __attribute__((ext_vector_type(4)))  float  floatx4;

__device__ __forceinline__ unsigned short f2bf(float f) {  // RNE f32->bf16
    unsigned u = __float_as_uint(f);
    u += 0x7fffu + ((u >> 16) & 1u);
    return (unsigned short)(u >> 16);
}
__device__ __forceinline__ float lrelu(float v) { return v >= 0.f ? v : 0.1f * v; }

// lgkm-only barrier: dw exchange visibility without draining the DMA queue.
#define SYNC_LDS() asm volatile("s_waitcnt lgkmcnt(0)\n\ts_barrier" ::: "memory")
// counted vmcnt wait (exact: after prologue the only vmem ops are our DMAs)
#define WAIT_VM(N) asm volatile("s_waitcnt vmcnt(" #N ")" ::: "memory")

typedef const __attribute__((address_space(1))) void* as1cv;
typedef __attribute__((address_space(3))) void*       as3v;

// ---------------------------------------------------------------------------
// Kernel-gen (unchanged, R5-proven). kernP[b][c][12] fp32; WcT transposed
// A-frag table (1KB-contiguous per wave fragment).
// ---------------------------------------------------------------------------
__global__ __launch_bounds__(192)
void gen_kern7(const float* __restrict__ d,
               const float* __restrict__ Wk1,
               const float* __restrict__ Wk2,
               const float* __restrict__ Wc,
               float* __restrict__ kernP,
               unsigned short* __restrict__ WcT) {
    const int b = blockIdx.x;
    const int r = blockIdx.y;
    const int t = threadIdx.x;
    __shared__ float hid_s[64];

    if (t < 64) {
        const float4* __restrict__ w4 = (const float4*)(Wk1 + (size_t)t * 64);
        const float*  __restrict__ db = d + b * 64;
        float s0 = 0.f, s1 = 0.f, s2 = 0.f, s3 = 0.f;
        #pragma unroll
        for (int j = 0; j < 16; ++j) {
            const float4 wv = w4[j];
            s0 += db[4 * j + 0] * wv.x;
            s1 += db[4 * j + 1] * wv.y;
            s2 += db[4 * j + 2] * wv.z;
            s3 += db[4 * j + 3] * wv.w;
        }
        hid_s[t] = lrelu((s0 + s1) + (s2 + s3));
    }
    __syncthreads();

    {
        const int o = r * 192 + t;
        const float4* __restrict__ w4 = (const float4*)(Wk2 + (size_t)o * 64);
        const float4* __restrict__ h4 = (const float4*)hid_s;
        float s0 = 0.f, s1 = 0.f, s2 = 0.f, s3 = 0.f;
        #pragma unroll
        for (int j = 0; j < 16; ++j) {
            const float4 wv = w4[j];
            const float4 hv = h4[j];
            s0 += hv.x * wv.x;
            s1 += hv.y * wv.y;
            s2 += hv.z * wv.z;
            s3 += hv.w * wv.w;
        }
        const int c = o / 9, tap = o - c * 9;
        kernP[b * 768 + c * 12 + tap] = (s0 + s1) + (s2 + s3);
    }

    if (b == 0 && r == 0) {
        for (int idx = t; idx < 4096; idx += 192) {
            const int j    = idx & 7;
            const int lane = (idx >> 3) & 63;
            const int g    = (idx >> 9) & 3;
            const int m    = idx >> 11;
            const int col  = lane & 31, kh = lane >> 5;
            const int o    = m * 32 + col;
            const int c    = g * 16 + kh * 8 + j;
            WcT[idx] = f2bf(Wc[o * 64 + c]);
        }
    }
}

// ---------------------------------------------------------------------------
// Main fused conv, R12: VGPR-free memory-level parallelism via
// global_load_lds DMA staging.
//   Diagnosis (R6-R11 invariant ~40-45us at 2.4 TB/s): register prefetch
//   keeps only ~86 B/lane duty-weighted in flight vs ~288 needed for 6.3
//   TB/s at ~900cy latency. Fix: DMA x directly to LDS (zero VGPR per
//   outstanding load). A full group (6 KB/wave) stays in flight across the
//   entire previous section; counted vmcnt(6) never drains the pipe
//   (a-frags/k hoisted to prologue regs, bias to epilogue -> after the
//   prologue the ONLY vmem ops are DMAs, so the count is exact).
//   xS slots are WAVE-PRIVATE (DMA of wave wv writes only slot(r,half,wv);
//   producer reads back only its own lane's 16B cells) => x path needs NO
//   barrier; the proven dw exchange keeps 4 disjoint buffers + 1 lgkm-only
//   barrier per group. Borders: DMA row clamped to h, then overwritten
//   with zeros via same-lane ds_write after the vmcnt wait (exact zero-pad).
//   LDS 64 KB -> 2 blocks/CU (8 waves/CU); DMA pipeline, not occupancy,
//   carries the latency. Numerics bit-identical to R7-R11.
// ---------------------------------------------------------------------------
struct XK { floatx4 x[3][2]; };                     // 3 rows x 8 px
struct KF { floatx4 k0, k1; float k8; };            // taps 0..3, 4..7, 8

__device__ __forceinline__ short8 compute_dw(const XK& v, const KF& kf,
                                             int lane, int tm) {
    float t0[8], t1[8], t2[8];                // column sums per dx
    #pragma unroll
    for (int i = 0; i < 8; ++i) {
        const float xr0 = (i < 4) ? v.x[0][0][i] : v.x[0][1][i - 4];
        const float xr1 = (i < 4) ? v.x[1][0][i] : v.x[1][1][i - 4];
        const float xr2 = (i < 4) ? v.x[2][0][i] : v.x[2][1][i - 4];
        t0[i] = kf.k0.x * xr0 + kf.k0.w * xr1 + kf.k1.z * xr2; // taps 0,3,6
        t1[i] = kf.k0.y * xr0 + kf.k1.x * xr1 + kf.k1.w * xr2; // taps 1,4,7
        t2[i] = kf.k0.z * xr0 + kf.k1.y * xr1 + kf.k8   * xr2; // taps 2,5,8
    }
    // halo from px-octet neighbors (same wave: tm>0 => lane-1 same wave)
    float t0m = __shfl(t0[7], lane - 1, 64);  // left  neighbor's t0[px0-1]
    float t2p = __shfl(t2[0], lane + 1, 64);  // right neighbor's t2[px0+8]
    if (tm == 0)  t0m = 0.f;                  // px = -1  border
    if (tm == 15) t2p = 0.f;                  // px = 128 border

    float dw[8];
    dw[0] = t0m + t1[0] + t2[1];
    #pragma unroll
    for (int i = 1; i < 7; ++i) dw[i] = t0[i - 1] + t1[i] + t2[i + 1];
    dw[7] = t0[6] + t1[7] + t2p;

    short8 w8;
    #pragma unroll
    for (int i = 0; i < 8; ++i) w8[i] = (short)f2bf(lrelu(dw[i]));
    return w8;
}

__global__ __launch_bounds__(256, 2)
void da_mfma8(const float* __restrict__ x,
              const float* __restrict__ kernP,
              const unsigned short* __restrict__ WcT,
              const float* __restrict__ bc,
              float* __restrict__ out) {
    const int t    = threadIdx.x;
    const int lane = t & 63;
    const int wv   = t >> 6;            // wave 0..3
    const int col  = lane & 31;         // consumer px within tile
    const int kh   = lane >> 5;         // consumer k-half
    const int bx   = blockIdx.x;        // 128
    const int h    = ((bx & 7) << 4) | (bx >> 3);   // XCD-band swizzle
    const int b    = blockIdx.y;        // 16
    const int px   = wv * 32 + col;

    // staging roles (same mapping as R7-R11; sch == wv*4 + (lane>>4))
    const int sch = t >> 4;             // channel within group, 0..15
    const int oct = t & 15;             // 8-px octet, 0..15
    const int px0 = oct * 8;

    // x staging: [buf][slot(r,half,wv)][1KB]; slots are wave-private.
    __shared__ float xS[2][24][256];               // 48 KB
    // dw exchange: one disjoint buffer per group (no WAR hazards).
    __shared__ unsigned short dwS[4][2048];        // 16 KB

    // clamped source rows + border flags (block-uniform)
    int hh[3];
    #pragma unroll
    for (int i = 0; i < 3; ++i) {
        const int hr = h + i - 1;
        hh[i] = (hr < 0) ? h : (hr >= Hn ? h : hr);
    }
    const bool oobTop = (h == 0);
    const bool oobBot = (h == Hn - 1);

    const float* __restrict__ xb = x + (size_t)b * Cn * HWn;
    const float* __restrict__ kp = kernP + b * 768;

    // ---- DMA issue helper (6 insts/group; zero VGPR held) ----
    auto dma_group = [&](int g) {
        float (&buf)[24][256] = xS[g & 1];
        #pragma unroll
        for (int r = 0; r < 3; ++r) {
            const float* gs = xb + (size_t)(g * 16 + sch) * HWn
                                 + (size_t)hh[r] * Wn + px0;
            __builtin_amdgcn_global_load_lds((as1cv)gs,
                (as3v)&buf[(r * 2 + 0) * 4 + wv][0], 16, 0, 0);
            __builtin_amdgcn_global_load_lds((as1cv)(gs + 4),
                (as3v)&buf[(r * 2 + 1) * 4 + wv][0], 16, 0, 0);
        }
    };

    floatx16 acc[2];
    #pragma unroll
    for (int m = 0; m < 2; ++m)
        #pragma unroll
        for (int r = 0; r < 16; ++r)
            acc[m][r] = 0.f;

    // ---- prologue: g0 DMA (oldest) -> a/k to regs -> g1 DMA (newest) ----
    dma_group(0);
    short8 a0s[4], a1s[4]; KF Kf[4];
    #pragma unroll
    for (int g = 0; g < 4; ++g) {
        a0s[g] = *(const short8*)(WcT + ((0 * 4 + g) * 64 + lane) * 8);
        a1s[g] = *(const short8*)(WcT + ((1 * 4 + g) * 64 + lane) * 8);
        const floatx4* k4 = (const floatx4*)(kp + (g * 16 + sch) * 12);
        Kf[g].k0 = k4[0];
        Kf[g].k1 = k4[1];
        Kf[g].k8 = ((const float*)k4)[8];
    }
    dma_group(1);

    // ---- section loop: DMA depth-1, counted vmcnt, 1 lgkm-barrier/group --
    #pragma unroll
    for (int g = 0; g < 4; ++g) {
        if (g >= 1 && g <= 2) dma_group(g + 1);
        if (g < 3) WAIT_VM(6); else WAIT_VM(0);   // g's x landed; next stays live

        const int tb = g & 1;
        if (oobTop) {   // overwrite clamped top row with zeros (own cells)
            const floatx4 z = {0.f, 0.f, 0.f, 0.f};
            *((floatx4*)&xS[tb][0 + wv][0] + lane) = z;
            *((floatx4*)&xS[tb][4 + wv][0] + lane) = z;
        }
        if (oobBot) {   // bottom row (r=2): slots 16+wv, 20+wv
            const floatx4 z = {0.f, 0.f, 0.f, 0.f};
            *((floatx4*)&xS[tb][16 + wv][0] + lane) = z;
            *((floatx4*)&xS[tb][20 + wv][0] + lane) = z;
        }

        XK v;   // read back own lane's staged x (wave-private slots)
        #pragma unroll
        for (int r = 0; r < 3; ++r) {
            v.x[r][0] = *((const floatx4*)&xS[tb][(r * 2 + 0) * 4 + wv][0] + lane);
            v.x[r][1] = *((const floatx4*)&xS[tb][(r * 2 + 1) * 4 + wv][0] + lane);
        }
        const short8 w8 = compute_dw(v, Kf[g], lane, oct);
        *(short8*)&dwS[g][sch * 128 + (px0 ^ ((sch & 8) << 2))] = w8;

        SYNC_LDS();   // lgkm-only: dw visible; DMA queue stays in flight

        short8 bfr;   // 8x ds_read_u16, XOR-32 swizzle (proven 0-conflict)
        #pragma unroll
        for (int j = 0; j < 8; ++j) {
            const int cl = kh * 8 + j;
            bfr[j] = (short)dwS[g][cl * 128 + (px ^ ((cl & 8) << 2))];
        }
        acc[0] = __builtin_amdgcn_mfma_f32_32x32x16_bf16(a0s[g], bfr, acc[0], 0, 0, 0);
        acc[1] = __builtin_amdgcn_mfma_f32_32x32x16_bf16(a1s[g], bfr, acc[1], 0, 0, 0);
    }

    // ---- STORE: full 128B lines; bias loaded here (after all DMA waits) ---
    float* __restrict__ ob = out + (size_t)b * Cn * HWn + h * Wn + px;
    #pragma unroll
    for (int m = 0; m < 2; ++m)
        #pragma unroll
        for (int q = 0; q < 4; ++q) {
            const float4 bv = *(const float4*)&bc[m * 32 + q * 8 + 4 * kh];
            #pragma unroll
            for (int j = 0; j < 4; ++j) {
                const int o = m * 32 + q * 8 + 4 * kh + j;
                ob[(size_t)o * HWn] = acc[m][q * 4 + j] + ((const float*)&bv)[j];
            }
        }
}

// ---------------------------------------------------------------------------
extern "C" void kernel_launch(void* const* d_in, const int* in_sizes, int n_in,
                              void* d_out, int out_size, void* d_ws, size_t ws_size,
                              hipStream_t stream) {
    const float* x   = (const float*)d_in[0];
    const float* d   = (const float*)d_in[1];
    const float* Wk1 = (const float*)d_in[2];
    const float* Wk2 = (const float*)d_in[3];
    const float* Wc  = (const float*)d_in[4];
    const float* bc  = (const float*)d_in[5];
    float* out = (float*)d_out;
    float*          kernP = (float*)d_ws;                              // 16*768 fp32
    unsigned short* WcT   = (unsigned short*)((float*)d_ws + Bn * 768); // 4096 bf16

    gen_kern7<<<dim3(Bn, 3), dim3(192), 0, stream>>>(d, Wk1, Wk2, Wc, kernP, WcT);
    da_mfma8<<<dim3(Hn, Bn), dim3(256), 0, stream>>>(x, kernP, WcT, bc, out);
}

// Round 8
// 133.240 us; speedup vs baseline: 1.0364x; 1.0364x over previous
//
#include <hip/hip_runtime.h>

#define Bn 16
#define Cn 64
#define Hn 128
#define Wn 128
#define HWn (Hn * Wn)

typedef __attribute__((ext_vector_type(8)))  short  short8;    // 8 bf16
typedef __attribute__((ext_vector_type(16))) float  floatx16;  // 32x32 C/D
typedef __attribute__((ext_vector_type(4)))  float  floatx4;
using int32x4 = int __attribute__((ext_vector_type(4)));

__device__ floatx4
llvm_amdgcn_raw_buffer_load_v4f32(int32x4 srsrc, int voffset, int soffset,
                                  int aux) __asm("llvm.amdgcn.raw.buffer.load.v4f32");

__device__ __forceinline__ int32x4 make_rsrc(const void* p, int bytes) {
    int32x4 r;
    r.x = (int)(unsigned)(uintptr_t)p;
    r.y = (int)((uintptr_t)p >> 32);   // stride=0
    r.z = bytes;                        // num_records
    r.w = 0x00020000;                   // raw dword SRD
    return r;
}

__device__ __forceinline__ unsigned short f2bf(float f) {  // RNE f32->bf16
    unsigned u = __float_as_uint(f);
    u += 0x7fffu + ((u >> 16) & 1u);
    return (unsigned short)(u >> 16);
}
__device__ __forceinline__ float lrelu(float v) { return v >= 0.f ? v : 0.1f * v; }

// lgkm-only barrier: dw-exchange visibility; register x-loads unaffected.
#define SYNC_LDS() asm volatile("s_waitcnt lgkmcnt(0)\n\ts_barrier" ::: "memory")

// ---------------------------------------------------------------------------
// Kernel-gen (unchanged, R5-proven). kernP[b][c][12] fp32; WcT transposed
// A-frag table (1KB-contiguous per wave fragment).
// ---------------------------------------------------------------------------
__global__ __launch_bounds__(192)
void gen_kern7(const float* __restrict__ d,
               const float* __restrict__ Wk1,
               const float* __restrict__ Wk2,
               const float* __restrict__ Wc,
               float* __restrict__ kernP,
               unsigned short* __restrict__ WcT) {
    const int b = blockIdx.x;
    const int r = blockIdx.y;
    const int t = threadIdx.x;
    __shared__ float hid_s[64];

    if (t < 64) {
        const float4* __restrict__ w4 = (const float4*)(Wk1 + (size_t)t * 64);
        const float*  __restrict__ db = d + b * 64;
        float s0 = 0.f, s1 = 0.f, s2 = 0.f, s3 = 0.f;
        #pragma unroll
        for (int j = 0; j < 16; ++j) {
            const float4 wv = w4[j];
            s0 += db[4 * j + 0] * wv.x;
            s1 += db[4 * j + 1] * wv.y;
            s2 += db[4 * j + 2] * wv.z;
            s3 += db[4 * j + 3] * wv.w;
        }
        hid_s[t] = lrelu((s0 + s1) + (s2 + s3));
    }
    __syncthreads();

    {
        const int o = r * 192 + t;
        const float4* __restrict__ w4 = (const float4*)(Wk2 + (size_t)o * 64);
        const float4* __restrict__ h4 = (const float4*)hid_s;
        float s0 = 0.f, s1 = 0.f, s2 = 0.f, s3 = 0.f;
        #pragma unroll
        for (int j = 0; j < 16; ++j) {
            const float4 wv = w4[j];
            const float4 hv = h4[j];
            s0 += hv.x * wv.x;
            s1 += hv.y * wv.y;
            s2 += hv.z * wv.z;
            s3 += hv.w * wv.w;
        }
        const int c = o / 9, tap = o - c * 9;
        kernP[b * 768 + c * 12 + tap] = (s0 + s1) + (s2 + s3);
    }

    if (b == 0 && r == 0) {
        for (int idx = t; idx < 4096; idx += 192) {
            const int j    = idx & 7;
            const int lane = (idx >> 3) & 63;
            const int g    = (idx >> 9) & 3;
            const int m    = idx >> 11;
            const int col  = lane & 31, kh = lane >> 5;
            const int o    = m * 32 + col;
            const int c    = g * 16 + kh * 8 + j;
            WcT[idx] = f2bf(Wc[o * 64 + c]);
        }
    }
}

// ---------------------------------------------------------------------------
// Main fused conv, R13: 4-ROW H-BANDS — fix DRAM access granularity.
//   Diagnosis: R12's counted-vmcnt DMA guaranteed 48-96 KB/CU outstanding
//   reads yet BW fell to 2.0 TB/s -> read MLP is NOT the limit. Invariant
//   across R6-R12 (~2.0-2.5 TB/s): every block touches DRAM in 512B runs
//   at 64KB stride (1 h-row per channel), both for writes (2/3 of traffic)
//   and reads. Scattered 512B granules ~ 30% HBM efficiency = the cap.
//   Fix: block covers 4 consecutive h rows:
//     * writes become 2KB contiguous per (block, channel) — 4x run length;
//     * 6 staged x rows serve 4 output rows (logical reads 3x -> 1.5x);
//     * MFMA per wave x4 (32 vs 8), acc[4][2] floatx16 = 128 VGPR.
//   Data path otherwise IDENTICAL to the measured-best R9 structure:
//   register staging (coalesced 512B/instr), dw exchange in LDS with the
//   proven XOR-32 swizzle, 2 alternating buffers + 1 lgkm-only barrier per
//   group (WAR-safe: W(g+2) is post-B(g+1); R(g) is pre-B(g+1)), depth-1
//   x-prefetch into the same X regs after their last use. Numerics
//   bit-identical (same tap sums, same RNE point; borders via OOB zeros).
// ---------------------------------------------------------------------------
struct KF { floatx4 k0, k1; float k8; };            // taps 0..3, 4..7, 8

__global__ __launch_bounds__(256, 2)
void da_mfma9(const float* __restrict__ x,
              const float* __restrict__ kernP,
              const unsigned short* __restrict__ WcT,
              const float* __restrict__ bc,
              float* __restrict__ out) {
    const int t    = threadIdx.x;
    const int lane = t & 63;
    const int wv   = t >> 6;            // wave 0..3 -> px tile
    const int col  = lane & 31;         // consumer: px within tile
    const int kh   = lane >> 5;         // consumer: k-half (8 ch)
    const int hbl  = blockIdx.x;        // 32 h-bands
    const int hb   = ((hbl & 7) << 2) | (hbl >> 3);   // XCD swizzle (bijective on 0..31)
    const int h0   = hb * 4;            // band rows h0..h0+3
    const int b    = blockIdx.y;        // 16
    const int px   = wv * 32 + col;

    // staging roles: sch = block-wide channel 0..15, oct = 8-px octet 0..15
    const int sch = t >> 4;
    const int oct = t & 15;
    const int px0 = oct * 8;

    // dw exchange: [buf][row][ch][px] bf16, XOR-32 px swizzle on ch bit3
    __shared__ unsigned short dwS[2][4][16][128];   // 32 KB

    // 6 staged x rows h0-1 .. h0+4; border -> OOB sentinel (loads return 0)
    int rofs[6];
    #pragma unroll
    for (int i = 0; i < 6; ++i) {
        const int hr = h0 + i - 1;
        rofs[i] = (hr >= 0 && hr < Hn) ? hr * (Wn * 4) : 0x10000000;
    }

    const int32x4 rs = make_rsrc(x + (size_t)b * Cn * HWn, Cn * HWn * 4);
    const float* __restrict__ kp = kernP + b * 768;

    floatx16 acc[4][2];
    #pragma unroll
    for (int r = 0; r < 4; ++r)
        #pragma unroll
        for (int m = 0; m < 2; ++m)
            #pragma unroll
            for (int e = 0; e < 16; ++e)
                acc[r][m][e] = 0.f;

    // x stage registers: 6 rows x 8 px (48 VGPR), reloaded per group after
    // last use (depth-1 prefetch at zero extra registers)
    floatx4 X[6][2];
    #define LOAD_X(G)                                                        \
        _Pragma("unroll")                                                    \
        for (int i = 0; i < 6; ++i) {                                        \
            const int vo = (((G) * 16 + sch) << 16) + rofs[i] + px0 * 4;     \
            X[i][0] = llvm_amdgcn_raw_buffer_load_v4f32(rs, vo, 0, 0);       \
            X[i][1] = llvm_amdgcn_raw_buffer_load_v4f32(rs, vo + 16, 0, 0);  \
        }

    LOAD_X(0);

    #pragma unroll
    for (int g = 0; g < 4; ++g) {
        const int buf = g & 1;
        KF kf;
        {
            const floatx4* k4 = (const floatx4*)(kp + (g * 16 + sch) * 12);
            kf.k0 = k4[0];
            kf.k1 = k4[1];
            kf.k8 = ((const float*)k4)[8];
        }

        // ---- produce dw for 4 output rows of this channel ----
        #pragma unroll
        for (int rr = 0; rr < 4; ++rr) {
            float t0[8], t1[8], t2[8];
            #pragma unroll
            for (int i = 0; i < 8; ++i) {
                const float xr0 = (i < 4) ? X[rr][0][i]     : X[rr][1][i - 4];
                const float xr1 = (i < 4) ? X[rr + 1][0][i] : X[rr + 1][1][i - 4];
                const float xr2 = (i < 4) ? X[rr + 2][0][i] : X[rr + 2][1][i - 4];
                t0[i] = kf.k0.x * xr0 + kf.k0.w * xr1 + kf.k1.z * xr2; // taps 0,3,6
                t1[i] = kf.k0.y * xr0 + kf.k1.x * xr1 + kf.k1.w * xr2; // taps 1,4,7
                t2[i] = kf.k0.z * xr0 + kf.k1.y * xr1 + kf.k8   * xr2; // taps 2,5,8
            }
            // horizontal halo from px-octet neighbor lanes (same wave)
            float t0m = __shfl(t0[7], lane - 1, 64);
            float t2p = __shfl(t2[0], lane + 1, 64);
            if (oct == 0)  t0m = 0.f;          // px = -1 border
            if (oct == 15) t2p = 0.f;          // px = 128 border

            float dw[8];
            dw[0] = t0m + t1[0] + t2[1];
            #pragma unroll
            for (int i = 1; i < 7; ++i) dw[i] = t0[i - 1] + t1[i] + t2[i + 1];
            dw[7] = t0[6] + t1[7] + t2p;

            short8 w8;
            #pragma unroll
            for (int i = 0; i < 8; ++i) w8[i] = (short)f2bf(lrelu(dw[i]));
            *(short8*)&dwS[buf][rr][sch][px0 ^ ((sch & 8) << 2)] = w8;
        }

        if (g < 3) { LOAD_X(g + 1); }   // prefetch rides under consume phase

        SYNC_LDS();   // lgkm-only: dw visible; x prefetch stays in flight

        // ---- consume: 4 rows x 2 MFMA ----
        const short8 a0 = *(const short8*)(WcT + ((0 * 4 + g) * 64 + lane) * 8);
        const short8 a1 = *(const short8*)(WcT + ((1 * 4 + g) * 64 + lane) * 8);
        #pragma unroll
        for (int rr = 0; rr < 4; ++rr) {
            short8 bfr;
            #pragma unroll
            for (int j = 0; j < 8; ++j) {
                const int cl = kh * 8 + j;
                bfr[j] = (short)dwS[buf][rr][cl][px ^ ((cl & 8) << 2)];
            }
            acc[rr][0] = __builtin_amdgcn_mfma_f32_32x32x16_bf16(a0, bfr, acc[rr][0], 0, 0, 0);
            acc[rr][1] = __builtin_amdgcn_mfma_f32_32x32x16_bf16(a1, bfr, acc[rr][1], 0, 0, 0);
        }
    }

    // ---- STORE: per (o): 4 rows x 128B from this wave -> block emits 2KB
    //      contiguous per channel. Inner loop walks rows (same 2KB run). ----
    float* __restrict__ ob = out + (size_t)b * Cn * HWn + (size_t)h0 * Wn + px;
    #pragma unroll
    for (int m = 0; m < 2; ++m)
        #pragma unroll
        for (int q = 0; q < 4; ++q) {
            const float4 bv = *(const float4*)&bc[m * 32 + q * 8 + 4 * kh];
            #pragma unroll
            for (int j = 0; j < 4; ++j) {
                const int o = m * 32 + q * 8 + 4 * kh + j;
                #pragma unroll
                for (int r = 0; r < 4; ++r)
                    ob[(size_t)o * HWn + r * Wn] = acc[r][m][q * 4 + j] + ((const float*)&bv)[j];
            }
        }
    #undef LOAD_X
}

// ---------------------------------------------------------------------------
extern "C" void kernel_launch(void* const* d_in, const int* in_sizes, int n_in,
                              void* d_out, int out_size, void* d_ws, size_t ws_size,
                              hipStream_t stream) {
    const float* x   = (const float*)d_in[0];
    const float* d   = (const float*)d_in[1];
    const float* Wk1 = (const float*)d_in[2];
    const float* Wk2 = (const float*)d_in[3];
    const float* Wc  = (const float*)d_in[4];
    const float* bc  = (const float*)d_in[5];
    float* out = (float*)d_out;
    float*          kernP = (float*)d_ws;                              // 16*768 fp32
    unsigned short* WcT   = (unsigned short*)((float*)d_ws + Bn * 768); // 4096 bf16

    gen_kern7<<<dim3(Bn, 3), dim3(192), 0, stream>>>(d, Wk1, Wk2, Wc, kernP, WcT);
    da_mfma9<<<dim3(Hn / 4, Bn), dim3(256), 0, stream>>>(x, kernP, WcT, bc, out);
}

// Round 9
// 126.138 us; speedup vs baseline: 1.0947x; 1.0563x over previous
//
#include <hip/hip_runtime.h>

#define Bn 16
#define Cn 64
#define Hn 128
#define Wn 128
#define HWn (Hn * Wn)

typedef __attribute__((ext_vector_type(8)))  short  short8;    // 8 bf16
typedef __attribute__((ext_vector_type(16))) float  floatx16;  // 32x32 C/D
typedef __attribute__((ext_vector_type(4)))  float  floatx4;
using int32x4 = int __attribute__((ext_vector_type(4)));

__device__ floatx4
llvm_amdgcn_raw_buffer_load_v4f32(int32x4 srsrc, int voffset, int soffset,
                                  int aux) __asm("llvm.amdgcn.raw.buffer.load.v4f32");

__device__ __forceinline__ int32x4 make_rsrc(const void* p, int bytes) {
    int32x4 r;
    r.x = (int)(unsigned)(uintptr_t)p;
    r.y = (int)((uintptr_t)p >> 32);   // stride=0
    r.z = bytes;                        // num_records
    r.w = 0x00020000;                   // raw dword SRD
    return r;
}

__device__ __forceinline__ unsigned short f2bf(float f) {  // RNE f32->bf16
    unsigned u = __float_as_uint(f);
    u += 0x7fffu + ((u >> 16) & 1u);
    return (unsigned short)(u >> 16);
}
__device__ __forceinline__ float lrelu(float v) { return v >= 0.f ? v : 0.1f * v; }

// lgkm-only barrier: LDS visibility; vmem (loads/nt-stores) stays in flight.
#define SYNC_LDS() asm volatile("s_waitcnt lgkmcnt(0)\n\ts_barrier" ::: "memory")

// ---------------------------------------------------------------------------
// Kernel-gen (unchanged, R5-proven). kernP[b][c][12] fp32; WcT transposed
// A-frag table (1KB-contiguous per wave fragment).
// ---------------------------------------------------------------------------
__global__ __launch_bounds__(192)
void gen_kern7(const float* __restrict__ d,
               const float* __restrict__ Wk1,
               const float* __restrict__ Wk2,
               const float* __restrict__ Wc,
               float* __restrict__ kernP,
               unsigned short* __restrict__ WcT) {
    const int b = blockIdx.x;
    const int r = blockIdx.y;
    const int t = threadIdx.x;
    __shared__ float hid_s[64];

    if (t < 64) {
        const float4* __restrict__ w4 = (const float4*)(Wk1 + (size_t)t * 64);
        const float*  __restrict__ db = d + b * 64;
        float s0 = 0.f, s1 = 0.f, s2 = 0.f, s3 = 0.f;
        #pragma unroll
        for (int j = 0; j < 16; ++j) {
            const float4 wv = w4[j];
            s0 += db[4 * j + 0] * wv.x;
            s1 += db[4 * j + 1] * wv.y;
            s2 += db[4 * j + 2] * wv.z;
            s3 += db[4 * j + 3] * wv.w;
        }
        hid_s[t] = lrelu((s0 + s1) + (s2 + s3));
    }
    __syncthreads();

    {
        const int o = r * 192 + t;
        const float4* __restrict__ w4 = (const float4*)(Wk2 + (size_t)o * 64);
        const float4* __restrict__ h4 = (const float4*)hid_s;
        float s0 = 0.f, s1 = 0.f, s2 = 0.f, s3 = 0.f;
        #pragma unroll
        for (int j = 0; j < 16; ++j) {
            const float4 wv = w4[j];
            const float4 hv = h4[j];
            s0 += hv.x * wv.x;
            s1 += hv.y * wv.y;
            s2 += hv.z * wv.z;
            s3 += hv.w * wv.w;
        }
        const int c = o / 9, tap = o - c * 9;
        kernP[b * 768 + c * 12 + tap] = (s0 + s1) + (s2 + s3);
    }

    if (b == 0 && r == 0) {
        for (int idx = t; idx < 4096; idx += 192) {
            const int j    = idx & 7;
            const int lane = (idx >> 3) & 63;
            const int g    = (idx >> 9) & 3;
            const int m    = idx >> 11;
            const int col  = lane & 31, kh = lane >> 5;
            const int o    = m * 32 + col;
            const int c    = g * 16 + kh * 8 + j;
            WcT[idx] = f2bf(Wc[o * 64 + c]);
        }
    }
}

// ---------------------------------------------------------------------------
// Main fused conv, R14: R13 main loop (verified) + FILL-LIKE WRITE EPILOGUE.
//   R13 post-mortem: per-wave store bursts were still 128B at 512B stride
//   (wave owns a px-quarter, rows 512B apart) — thousands of concurrent
//   128B-granule write streams cap HBM at ~2.5 TB/s (fill kernel with long
//   sequential per-wave runs: 6.4 TB/s). R12 ruled out read-MLP.
//   Fix: LDS-transpose epilogue. acc -> 32KB fp32 scratch (aliases the
//   dead dwS buffer) in 4 rounds of 16 channels; read back so each wave
//   stores a channel's ENTIRE 2KB band (4 rows x 128px) as 8 back-to-back
//   1KB dwordx4 NON-TEMPORAL stores (no L2 write-allocate churn; L2/L3
//   capacity left for x). Stored values bit-identical (same acc + bias).
//   Cost: 8 lgkm-only barriers + ~40 LDS ops/lane (<0.5us/block).
// ---------------------------------------------------------------------------
struct KF { floatx4 k0, k1; float k8; };            // taps 0..3, 4..7, 8

__global__ __launch_bounds__(256, 2)
void da_mfma10(const float* __restrict__ x,
               const float* __restrict__ kernP,
               const unsigned short* __restrict__ WcT,
               const float* __restrict__ bc,
               float* __restrict__ out) {
    const int t    = threadIdx.x;
    const int lane = t & 63;
    const int wv   = t >> 6;            // wave 0..3 -> px tile
    const int col  = lane & 31;         // consumer: px within tile
    const int kh   = lane >> 5;         // consumer: k-half (8 ch)
    const int hbl  = blockIdx.x;        // 32 h-bands
    const int hb   = ((hbl & 7) << 2) | (hbl >> 3);   // XCD swizzle (bijective)
    const int h0   = hb * 4;            // band rows h0..h0+3
    const int b    = blockIdx.y;        // 16
    const int px   = wv * 32 + col;

    // staging roles: sch = block-wide channel 0..15, oct = 8-px octet 0..15
    const int sch = t >> 4;
    const int oct = t & 15;
    const int px0 = oct * 8;

    // 32KB shared, dual-purpose:
    //   main loop: dw exchange [buf][row][ch][px] bf16 (XOR-32 px swizzle)
    //   epilogue:  fp32 transpose scratch [16ch][4r*128px]
    __shared__ unsigned char smem[32768];
    auto dwS = reinterpret_cast<unsigned short (*)[4][16][128]>(smem); // [2][4][16][128]
    float* eT = reinterpret_cast<float*>(smem);

    // 6 staged x rows h0-1 .. h0+4; border -> OOB sentinel (loads return 0)
    int rofs[6];
    #pragma unroll
    for (int i = 0; i < 6; ++i) {
        const int hr = h0 + i - 1;
        rofs[i] = (hr >= 0 && hr < Hn) ? hr * (Wn * 4) : 0x10000000;
    }

    const int32x4 rs = make_rsrc(x + (size_t)b * Cn * HWn, Cn * HWn * 4);
    const float* __restrict__ kp = kernP + b * 768;

    floatx16 acc[4][2];
    #pragma unroll
    for (int r = 0; r < 4; ++r)
        #pragma unroll
        for (int m = 0; m < 2; ++m)
            #pragma unroll
            for (int e = 0; e < 16; ++e)
                acc[r][m][e] = 0.f;

    floatx4 X[6][2];
    #define LOAD_X(G)                                                        \
        _Pragma("unroll")                                                    \
        for (int i = 0; i < 6; ++i) {                                        \
            const int vo = (((G) * 16 + sch) << 16) + rofs[i] + px0 * 4;     \
            X[i][0] = llvm_amdgcn_raw_buffer_load_v4f32(rs, vo, 0, 0);       \
            X[i][1] = llvm_amdgcn_raw_buffer_load_v4f32(rs, vo + 16, 0, 0);  \
        }

    LOAD_X(0);

    #pragma unroll
    for (int g = 0; g < 4; ++g) {
        const int buf = g & 1;
        KF kf;
        {
            const floatx4* k4 = (const floatx4*)(kp + (g * 16 + sch) * 12);
            kf.k0 = k4[0];
            kf.k1 = k4[1];
            kf.k8 = ((const float*)k4)[8];
        }

        // ---- produce dw for 4 output rows of this channel ----
        #pragma unroll
        for (int rr = 0; rr < 4; ++rr) {
            float t0[8], t1[8], t2[8];
            #pragma unroll
            for (int i = 0; i < 8; ++i) {
                const float xr0 = (i < 4) ? X[rr][0][i]     : X[rr][1][i - 4];
                const float xr1 = (i < 4) ? X[rr + 1][0][i] : X[rr + 1][1][i - 4];
                const float xr2 = (i < 4) ? X[rr + 2][0][i] : X[rr + 2][1][i - 4];
                t0[i] = kf.k0.x * xr0 + kf.k0.w * xr1 + kf.k1.z * xr2; // taps 0,3,6
                t1[i] = kf.k0.y * xr0 + kf.k1.x * xr1 + kf.k1.w * xr2; // taps 1,4,7
                t2[i] = kf.k0.z * xr0 + kf.k1.y * xr1 + kf.k8   * xr2; // taps 2,5,8
            }
            float t0m = __shfl(t0[7], lane - 1, 64);
            float t2p = __shfl(t2[0], lane + 1, 64);
            if (oct == 0)  t0m = 0.f;          // px = -1 border
            if (oct == 15) t2p = 0.f;          // px = 128 border

            float dw[8];
            dw[0] = t0m + t1[0] + t2[1];
            #pragma unroll
            for (int i = 1; i < 7; ++i) dw[i] = t0[i - 1] + t1[i] + t2[i + 1];
            dw[7] = t0[6] + t1[7] + t2p;

            short8 w8;
            #pragma unroll
            for (int i = 0; i < 8; ++i) w8[i] = (short)f2bf(lrelu(dw[i]));
            *(short8*)&dwS[buf][rr][sch][px0 ^ ((sch & 8) << 2)] = w8;
        }

        if (g < 3) { LOAD_X(g + 1); }   // prefetch rides under consume phase

        SYNC_LDS();   // lgkm-only: dw visible; x prefetch stays in flight

        const short8 a0 = *(const short8*)(WcT + ((0 * 4 + g) * 64 + lane) * 8);
        const short8 a1 = *(const short8*)(WcT + ((1 * 4 + g) * 64 + lane) * 8);
        #pragma unroll
        for (int rr = 0; rr < 4; ++rr) {
            short8 bfr;
            #pragma unroll
            for (int j = 0; j < 8; ++j) {
                const int cl = kh * 8 + j;
                bfr[j] = (short)dwS[buf][rr][cl][px ^ ((cl & 8) << 2)];
            }
            acc[rr][0] = __builtin_amdgcn_mfma_f32_32x32x16_bf16(a0, bfr, acc[rr][0], 0, 0, 0);
            acc[rr][1] = __builtin_amdgcn_mfma_f32_32x32x16_bf16(a1, bfr, acc[rr][1], 0, 0, 0);
        }
    }
    #undef LOAD_X

    // ---- EPILOGUE: LDS transpose -> fill-like nt write streams ----
    // 4 rounds (m, bh): 16 channels o = m*32 + bh*16 + o16,
    //   o16 = (q&3) + 4*kh + 8*(q>>2) for acc element e = bh*8+q.
    // Write: 32 ds_write_b32/lane (bank = col, 2-way: free).
    // Read:  lane (o_r = t>>4, rem = t&15): channel o_r's 2KB band as
    //   8 float4 at slot rem+16k -> 8 back-to-back 1KB store instrs;
    //   each channel's 2KB written contiguously by one wave, nt.
    floatx4* __restrict__ o4 = (floatx4*)(out + (size_t)b * Cn * HWn);
    const int o_r = t >> 4, rem = t & 15;
    #pragma unroll
    for (int m = 0; m < 2; ++m)
        #pragma unroll
        for (int bh = 0; bh < 2; ++bh) {
            SYNC_LDS();   // protect prior round's reads / last dwS reads
            #pragma unroll
            for (int q = 0; q < 8; ++q) {
                const int o16 = (q & 3) + 4 * kh + 8 * (q >> 2);
                #pragma unroll
                for (int r = 0; r < 4; ++r)
                    eT[o16 * 512 + r * 128 + wv * 32 + col] = acc[r][m][bh * 8 + q];
            }
            SYNC_LDS();   // transpose visible
            const int   og = m * 32 + bh * 16 + o_r;
            const float bv = bc[og];
            #pragma unroll
            for (int k = 0; k < 8; ++k) {
                floatx4 v = *((const floatx4*)eT + o_r * 128 + rem + 16 * k);
                v.x += bv; v.y += bv; v.z += bv; v.w += bv;
                __builtin_nontemporal_store(
                    v, &o4[(size_t)og * (HWn / 4) + h0 * (Wn / 4) + rem + 16 * k]);
            }
        }
}

// ---------------------------------------------------------------------------
extern "C" void kernel_launch(void* const* d_in, const int* in_sizes, int n_in,
                              void* d_out, int out_size, void* d_ws, size_t ws_size,
                              hipStream_t stream) {
    const float* x   = (const float*)d_in[0];
    const float* d   = (const float*)d_in[1];
    const float* Wk1 = (const float*)d_in[2];
    const float* Wk2 = (const float*)d_in[3];
    const float* Wc  = (const float*)d_in[4];
    const float* bc  = (const float*)d_in[5];
    float* out = (float*)d_out;
    float*          kernP = (float*)d_ws;                              // 16*768 fp32
    unsigned short* WcT   = (unsigned short*)((float*)d_ws + Bn * 768); // 4096 bf16

    gen_kern7<<<dim3(Bn, 3), dim3(192), 0, stream>>>(d, Wk1, Wk2, Wc, kernP, WcT);
    da_mfma10<<<dim3(Hn / 4, Bn), dim3(256), 0, stream>>>(x, kernP, WcT, bc, out);
}